// Round 21
// baseline (67.357 us; speedup 1.0000x reference)
//
#include <hip/hip_runtime.h>
#include <math.h>

#define B_ 64
#define L_ 512
#define N_ 321
#define P_ 720
#define E_ 8
#define R_ 32
#define CID_ 32
#define H_ 64
#define ER_ 256
#define KB2 288      // ER_ + 8 bias-rank + 1 mean + 23 zero-pad
#define HGROWS 384   // gemm2 tiles read 64-row chunks; rows >= 352 hold junk, outputs discarded

typedef __attribute__((ext_vector_type(8))) short bf16x8;
typedef __attribute__((ext_vector_type(4))) float f32x4;
typedef __attribute__((ext_vector_type(8))) unsigned short u16x8;
typedef __attribute__((ext_vector_type(4))) unsigned short u16x4;
typedef __attribute__((ext_vector_type(2))) unsigned short u16x2;

// workspace layout (float offsets)
#define OFF_GATE 0                        // 2568
#define OFF_CS1  2568                     // 256
#define OFF_W1K  2824                     // bf16 256*512 = 65536 f
#define OFF_W2X  68360                    // bf16 720*288 = 103680 f
#define OFF_HG   172040                   // bf16 64*384*288 = 3538944 f
// total ~14.8 MB

__device__ __forceinline__ unsigned short f2bf(float f) {
    unsigned u = __float_as_uint(f);
    u += 0x7fffu + ((u >> 16) & 1u);
    return (unsigned short)(u >> 16);
}
__device__ __forceinline__ float bf2f(unsigned short h) {
    return __uint_as_float(((unsigned)h) << 16);
}

// ---------------- prep: w1k, w2x, cs1, router (merged) ----------------------
__global__ void prep_kernel(const float* __restrict__ w1, const float* __restrict__ w2,
                            const float* __restrict__ bias,
                            const float* __restrict__ ident,
                            const float* __restrict__ rw1, const float* __restrict__ rb1,
                            const float* __restrict__ rw2, const float* __restrict__ rb2,
                            unsigned short* __restrict__ w1k, unsigned short* __restrict__ w2x,
                            float* __restrict__ cs1, float* __restrict__ gate) {
    __shared__ float red[16][32];
    __shared__ float hid[H_];
    __shared__ float lg[E_];
    int bid = blockIdx.x, t = threadIdx.x;
    if (bid < 128) {                  // w1k [er][l]: 256*512 elems, 512 thr x 2
        #pragma unroll
        for (int r = 0; r < 2; ++r) {
            int g = bid*1024 + r*512 + t;
            int er = g >> 9, l = g & 511;
            w1k[g] = f2bf(w1[(size_t)(er >> 5)*(L_*R_) + (size_t)l*R_ + (er & 31)]);
        }
    } else if (bid < 848) {           // w2x row p: K-extended
        int p = bid - 128;
        if (t < KB2) {
            unsigned short v;
            if (t < ER_)            v = f2bf(w2[(size_t)t*P_ + p]);
            else if (t < ER_ + E_)  v = f2bf(bias[(size_t)(t - ER_)*P_ + p]);
            else if (t == ER_ + E_) v = 0x3f80;  // bf16(1.0) for the mean lane
            else                    v = 0;
            w2x[(size_t)p*KB2 + t] = v;
        }
    } else if (bid < 856) {           // cs1: 8 blocks, one expert each (512 thr)
        int e = bid - 848;
        int q = t >> 5, r = t & 31;
        float s = 0.f;
        for (int l = q; l < L_; l += 16)
            s += bf2f(f2bf(w1[(size_t)e*(L_*R_) + (size_t)l*R_ + r]));
        red[q][r] = s;
        __syncthreads();
        if (q == 0) {
            #pragma unroll
            for (int qq = 1; qq < 16; ++qq) s += red[qq][r];
            cs1[e*32 + r] = s;
        }
    } else {                          // router: one n per block (t<64 active)
        int n = bid - 856;
        if (t < H_) {
            float acc = rb1[t];
            #pragma unroll
            for (int c = 0; c < CID_; ++c)
                acc = fmaf(ident[n*CID_ + c], rw1[c*H_ + t], acc);
            hid[t] = fmaxf(acc, 0.f);
        }
        __syncthreads();
        if (t < E_) {
            float a = rb2[t];
            #pragma unroll
            for (int h = 0; h < H_; ++h) a = fmaf(hid[h], rw2[h*E_ + t], a);
            lg[t] = a;
        }
        __syncthreads();
        if (t == 0) {
            float m = lg[0];
            #pragma unroll
            for (int e = 1; e < E_; ++e) m = fmaxf(m, lg[e]);
            float s = 0.f, ex[E_];
            #pragma unroll
            for (int e = 0; e < E_; ++e) { ex[e] = expf(lg[e] - m); s += ex[e]; }
            float inv = 1.f / s;
            #pragma unroll
            for (int e = 0; e < E_; ++e) gate[n*E_ + e] = ex[e] * inv;
        }
    }
}

// ---------------- GEMM1: bulk free-running load, then MFMA ------------------
// grid 704 = 8 xcd * (8 b * 11 nt), 512 thr, (512,4) ~128 VGPR, 2 blocks/CU.
// Phase 1: thread (xn=tid&31, ks=tid>>5) issues ALL 32 strided x-loads into
// v[32] with no intervening consumers (stats-kernel pattern -> full MLP),
// then converts+stats+stores to 32KB swizzled LDS. One barrier.
// Phase 2: wave owns 32er x 32n x K=512; af-ring from L2-hot w1k; epilogue
// gate*(acc - mean*cs1) + K-ext. No er duplication: x read once.
__global__ __launch_bounds__(512, 4) void gemm1_kernel(
        const float* __restrict__ x, const unsigned short* __restrict__ w1k,
        const float* __restrict__ gate, const float* __restrict__ cs1,
        unsigned short* __restrict__ hg) {
    __shared__ __align__(16) unsigned short xL[32 * 512];   // 32768 B, swizzled
    __shared__ float red1[16][32], red2[16][32];            // 4096 B
    __shared__ float meanS[32], sdS[32];

    const int bid = blockIdx.x;
    const int xcd = bid & 7;
    const int idx = bid >> 3;            // 0..87
    const int b   = (xcd << 3) + idx / 11;
    const int n0  = (idx % 11) * 32;

    const int tid  = threadIdx.x;
    const int lane = tid & 63;
    const int wave = tid >> 6;          // 0..7
    const int l15  = lane & 15;
    const int kgrp = lane >> 4;         // 0..3

    // ---- phase 1: bulk load (free-running), convert+stats+store ----
    const int xn = tid & 31;
    const int ks = tid >> 5;            // 0..15, 32 k each
    const int gn = n0 + xn;
    const int gnc = (gn < N_) ? gn : (N_ - 1);
    const float* xp = x + (size_t)b*L_*N_ + gnc + (size_t)(ks*32)*N_;

    float v[32];
    #pragma unroll
    for (int i = 0; i < 32; ++i)
        v[i] = xp[(size_t)i * N_];      // 32 independent loads, no consumers

    float s1 = 0.f, s2 = 0.f;
    {
        const int swz = (xn & 7) << 4;
        char* dst = (char*)xL + xn*1024;
        #pragma unroll
        for (int j = 0; j < 4; ++j) {
            u16x8 pk;
            #pragma unroll
            for (int q = 0; q < 8; ++q) {
                float f = v[j*8 + q];
                s1 += f; s2 = fmaf(f, f, s2);
                pk[q] = f2bf(f);
            }
            *(u16x8*)(dst + ((ks*64 + j*16) ^ swz)) = pk;
        }
    }
    red1[ks][xn] = s1;
    red2[ks][xn] = s2;
    __syncthreads();
    if (tid < 32) {
        float a = 0.f, qq = 0.f;
        #pragma unroll
        for (int kk = 0; kk < 16; ++kk) { a += red1[kk][tid]; qq += red2[kk][tid]; }
        float mean = a * (1.f/L_);
        float var = (qq - (float)L_*mean*mean) * (1.f/(L_-1));
        var = fmaxf(var, 0.f);
        meanS[tid] = mean;
        sdS[tid]   = sqrtf(var) + 1e-6f;
    }
    __syncthreads();

    // ---- phase 2: MFMA, wave owns er rows wave*32..+32, K=512 (16 kk) ----
    const unsigned short* apA = w1k + (size_t)(wave*32 + l15)*L_;
    const unsigned short* apB = w1k + (size_t)(wave*32 + 16 + l15)*L_;
    const int rsw = (l15 & 7) << 4;     // rows l15 and 16+l15 share the XOR

    f32x4 acc[2][2];
    #pragma unroll
    for (int i = 0; i < 2; ++i)
        #pragma unroll
        for (int j = 0; j < 2; ++j) acc[i][j] = (f32x4){0.f,0.f,0.f,0.f};

    bf16x8 af[4][2];
#define LDA(s_, kk_) { af[s_][0] = *(const bf16x8*)&apA[(kk_)*32 + kgrp*8];      \
                       af[s_][1] = *(const bf16x8*)&apB[(kk_)*32 + kgrp*8]; }
    LDA(0, 0); LDA(1, 1);
    #pragma unroll
    for (int kk = 0; kk < 16; ++kk) {
        if (kk + 2 < 16) LDA((kk + 2) & 3, kk + 2);
        const int cb = kk*64 + kgrp*16;
        bf16x8 b0 = *(const bf16x8*)((char*)xL + l15*1024        + (cb ^ rsw));
        bf16x8 b1 = *(const bf16x8*)((char*)xL + (16 + l15)*1024 + (cb ^ rsw));
        acc[0][0] = __builtin_amdgcn_mfma_f32_16x16x32_bf16(af[kk & 3][0], b0, acc[0][0], 0, 0, 0);
        acc[0][1] = __builtin_amdgcn_mfma_f32_16x16x32_bf16(af[kk & 3][0], b1, acc[0][1], 0, 0, 0);
        acc[1][0] = __builtin_amdgcn_mfma_f32_16x16x32_bf16(af[kk & 3][1], b0, acc[1][0], 0, 0, 0);
        acc[1][1] = __builtin_amdgcn_mfma_f32_16x16x32_bf16(af[kk & 3][1], b1, acc[1][1], 0, 0, 0);
    }
#undef LDA

    // ---- epilogue: hg[b][n0+nl][er] = gate*(acc - mean*cs1), + K-ext ----
    unsigned short* hgb = hg + ((size_t)b * HGROWS + n0) * KB2;
    #pragma unroll
    for (int fm = 0; fm < 2; ++fm) {
        int er0 = wave*32 + fm*16 + kgrp*4;
        int e = er0 >> 5;
        f32x4 c4 = *(const f32x4*)&cs1[er0];
        #pragma unroll
        for (int fn = 0; fn < 2; ++fn) {
            int nl = fn*16 + l15;
            int gnn = n0 + nl; if (gnn > N_-1) gnn = N_-1;
            float g = gate[gnn*E_ + e];
            float m = meanS[nl];
            u16x4 pk;
            #pragma unroll
            for (int j = 0; j < 4; ++j)
                pk[j] = f2bf(g * (acc[fm][fn][j] - m * c4[j]));
            *(u16x4*)&hgb[(size_t)nl*KB2 + er0] = pk;
        }
    }
    {   // K-extension cols 256..287: 32 rows x 16 segs x 2 cols
        int nl = tid >> 4, sg = tid & 15;
        int gnn = n0 + nl; if (gnn > N_-1) gnn = N_-1;
        float sd = sdS[nl], m = meanS[nl];
        u16x2 pk;
        #pragma unroll
        for (int jj = 0; jj < 2; ++jj) {
            int k = sg*2 + jj;
            float vv = (k < E_) ? gate[gnn*E_ + k] * sd : ((k == E_) ? m : 0.f);
            pk[jj] = f2bf(vv);
        }
        *(u16x2*)&hgb[(size_t)nl*KB2 + ER_ + sg*2] = pk;
    }
}

// ---------------- GEMM2: out = w2x . hg^T, one LDS stage + barrier ----------
// grid 2304 = 8 xcd * (8 b * (6 pt * 6 nt)); BM=128 p, BN=64 n, K=288.
#define HGS 296   // u16 LDS stride (148 dw -> 2-way aliasing, free)
__global__ __launch_bounds__(512, 6) void gemm2_kernel(
        const unsigned short* __restrict__ hg, const unsigned short* __restrict__ w2x,
        float* __restrict__ out) {
    __shared__ __align__(16) char smem[64 * HGS * 2];      // 37888 B
    unsigned short* hgL = (unsigned short*)smem;           // [64][296]
    const int bid = blockIdx.x;
    const int xcd = bid & 7;
    const int idx = bid >> 3;            // 0..287
    const int b   = (xcd << 3) + idx / 36;
    const int rem = idx % 36;
    const int p0  = (rem / 6) * 128;
    const int n0  = (rem % 6) * 64;

    const int tid  = threadIdx.x;
    const int lane = tid & 63;
    const int wave = tid >> 6;
    const int l15  = lane & 15;
    const int kgrp = lane >> 4;

    // stage hg tile [64][288] -> LDS (16B chunks, 36 per row)
    const unsigned short* hgb = hg + ((size_t)b * HGROWS + n0) * KB2;
    #pragma unroll
    for (int it = 0; it < 5; ++it) {
        int c = tid + it*512;
        if (c < 64*36) {
            int row = c / 36, col = c % 36;
            *(u16x8*)&hgL[(size_t)row*HGS + col*8] =
                *(const u16x8*)&hgb[(size_t)row*KB2 + col*8];
        }
    }
    __syncthreads();

    // K-loop: wave owns 16 p-rows; A-frags from L2-hot w2x, B-frags from LDS
    int prow = p0 + wave*16 + l15; if (prow > P_-1) prow = P_-1;
    const unsigned short* ap = w2x + (size_t)prow*KB2;
    f32x4 o[4];
    #pragma unroll
    for (int j = 0; j < 4; ++j) o[j] = (f32x4){0.f,0.f,0.f,0.f};
    #pragma unroll
    for (int ks = 0; ks < 9; ++ks) {
        bf16x8 afr = *(const bf16x8*)&ap[ks*32 + kgrp*8];
        #pragma unroll
        for (int fn = 0; fn < 4; ++fn) {
            bf16x8 bfr = *(const bf16x8*)&hgL[(size_t)(fn*16 + l15)*HGS + ks*32 + kgrp*8];
            o[fn] = __builtin_amdgcn_mfma_f32_16x16x32_bf16(afr, bfr, o[fn], 0, 0, 0);
        }
    }
    __syncthreads();   // all waves done reading hgL; patch may overwrite

    // patch-transpose: D rows p_loc = kgrp*4+j, cols n_loc = fn*16+l15
    float* patch = (float*)smem + wave * 1088;   // [16][68] f32 = 4352 B
    #pragma unroll
    for (int fn = 0; fn < 4; ++fn)
        #pragma unroll
        for (int j = 0; j < 4; ++j)
            patch[(kgrp*4 + j)*68 + fn*16 + l15] = o[fn][j];
    const int pw0 = p0 + wave*16;
    #pragma unroll
    for (int pass = 0; pass < 4; ++pass) {
        int ploc = pass*4 + kgrp;
        f32x4 v = *(const f32x4*)&patch[ploc*68 + l15*4];
        int p = pw0 + ploc;
        int n = n0 + l15*4;
        if (p < P_) {
            float* orow = out + ((size_t)b*P_ + p)*N_;
            if (n + 3 < N_) {
                *(f32x4*)&orow[n] = v;
            } else {
                #pragma unroll
                for (int j = 0; j < 4; ++j)
                    if (n + j < N_) orow[n + j] = v[j];
            }
        }
    }
}

extern "C" void kernel_launch(void* const* d_in, const int* in_sizes, int n_in,
                              void* d_out, int out_size, void* d_ws, size_t ws_size,
                              hipStream_t stream) {
    const float* x     = (const float*)d_in[0];
    const float* ident = (const float*)d_in[1];
    const float* rw1   = (const float*)d_in[2];
    const float* rb1   = (const float*)d_in[3];
    const float* rw2   = (const float*)d_in[4];
    const float* rb2   = (const float*)d_in[5];
    const float* w1    = (const float*)d_in[6];
    const float* w2    = (const float*)d_in[7];
    const float* bias  = (const float*)d_in[8];
    float* out = (float*)d_out;
    float* ws  = (float*)d_ws;

    float* gate = ws + OFF_GATE;
    float* cs1  = ws + OFF_CS1;
    unsigned short* w1k = (unsigned short*)(ws + OFF_W1K);
    unsigned short* w2x = (unsigned short*)(ws + OFF_W2X);
    unsigned short* hg  = (unsigned short*)(ws + OFF_HG);

    prep_kernel<<<856 + N_, 512, 0, stream>>>(w1, w2, bias, ident, rw1, rb1,
                                              rw2, rb2, w1k, w2x, cs1, gate);
    gemm1_kernel<<<dim3(704), 512, 0, stream>>>(x, w1k, gate, cs1, hg);
    gemm2_kernel<<<dim3(2304), 512, 0, stream>>>(hg, w2x, out);
}

// Round 22
// 64.345 us; speedup vs baseline: 1.0468x; 1.0468x over previous
//
#include <hip/hip_runtime.h>
#include <math.h>

#define B_ 64
#define L_ 512
#define N_ 321
#define P_ 720
#define E_ 8
#define R_ 32
#define CID_ 32
#define H_ 64
#define ER_ 256
#define KB2 288      // ER_ + 8 bias-rank + 1 mean + 23 zero-pad
#define HGROWS 384   // 6 n-tiles x 64 (rows >= N_ hold dup/junk, never used)

typedef __attribute__((ext_vector_type(8))) short bf16x8;
typedef __attribute__((ext_vector_type(4))) float f32x4;
typedef __attribute__((ext_vector_type(8))) unsigned short u16x8;
typedef __attribute__((ext_vector_type(4))) unsigned short u16x4;

// workspace layout (float offsets)
#define OFF_GATE 0                        // 2568
#define OFF_CS1  2568                     // 256
#define OFF_W1K  2824                     // bf16 256*512 = 65536 f
#define OFF_W2X  68360                    // bf16 720*288 = 103680 f
#define OFF_HG   172040                   // bf16 64*384*288 = 3538944 f
// total ~14.8 MB

__device__ __forceinline__ unsigned short f2bf(float f) {
    unsigned u = __float_as_uint(f);
    u += 0x7fffu + ((u >> 16) & 1u);
    return (unsigned short)(u >> 16);
}
__device__ __forceinline__ float bf2f(unsigned short h) {
    return __uint_as_float(((unsigned)h) << 16);
}

// async global->LDS DMA: per-lane global src, wave-uniform LDS base + lane*4
#define GLD4(gsrc, ldst)                                                        \
    __builtin_amdgcn_global_load_lds(                                           \
        (const __attribute__((address_space(1))) unsigned*)(gsrc),              \
        (__attribute__((address_space(3))) unsigned*)(ldst), 4, 0, 0)

// ---------------- prep: w1k, w2x, cs1, router (merged) ----------------------
__global__ void prep_kernel(const float* __restrict__ w1, const float* __restrict__ w2,
                            const float* __restrict__ bias,
                            const float* __restrict__ ident,
                            const float* __restrict__ rw1, const float* __restrict__ rb1,
                            const float* __restrict__ rw2, const float* __restrict__ rb2,
                            unsigned short* __restrict__ w1k, unsigned short* __restrict__ w2x,
                            float* __restrict__ cs1, float* __restrict__ gate) {
    __shared__ float red[16][32];
    __shared__ float hid[H_];
    __shared__ float lg[E_];
    int bid = blockIdx.x, t = threadIdx.x;
    if (bid < 128) {                  // w1k [er][l]: 256*512 elems, 512 thr x 2
        #pragma unroll
        for (int r = 0; r < 2; ++r) {
            int g = bid*1024 + r*512 + t;
            int er = g >> 9, l = g & 511;
            w1k[g] = f2bf(w1[(size_t)(er >> 5)*(L_*R_) + (size_t)l*R_ + (er & 31)]);
        }
    } else if (bid < 848) {           // w2x row p: K-extended
        int p = bid - 128;
        if (t < KB2) {
            unsigned short v;
            if (t < ER_)            v = f2bf(w2[(size_t)t*P_ + p]);
            else if (t < ER_ + E_)  v = f2bf(bias[(size_t)(t - ER_)*P_ + p]);
            else if (t == ER_ + E_) v = 0x3f80;  // bf16(1.0) for the mean lane
            else                    v = 0;
            w2x[(size_t)p*KB2 + t] = v;
        }
    } else if (bid < 856) {           // cs1: 8 blocks, one expert each (512 thr)
        int e = bid - 848;
        int q = t >> 5, r = t & 31;
        float s = 0.f;
        for (int l = q; l < L_; l += 16)
            s += bf2f(f2bf(w1[(size_t)e*(L_*R_) + (size_t)l*R_ + r]));
        red[q][r] = s;
        __syncthreads();
        if (q == 0) {
            #pragma unroll
            for (int qq = 1; qq < 16; ++qq) s += red[qq][r];
            cs1[e*32 + r] = s;
        }
    } else {                          // router: one n per block (t<64 active)
        int n = bid - 856;
        if (t < H_) {
            float acc = rb1[t];
            #pragma unroll
            for (int c = 0; c < CID_; ++c)
                acc = fmaf(ident[n*CID_ + c], rw1[c*H_ + t], acc);
            hid[t] = fmaxf(acc, 0.f);
        }
        __syncthreads();
        if (t < E_) {
            float a = rb2[t];
            #pragma unroll
            for (int h = 0; h < H_; ++h) a = fmaf(hid[h], rw2[h*E_ + t], a);
            lg[t] = a;
        }
        __syncthreads();
        if (t == 0) {
            float m = lg[0];
            #pragma unroll
            for (int e = 1; e < E_; ++e) m = fmaxf(m, lg[e]);
            float s = 0.f, ex[E_];
            #pragma unroll
            for (int e = 0; e < E_; ++e) { ex[e] = expf(lg[e] - m); s += ex[e]; }
            float inv = 1.f / s;
            #pragma unroll
            for (int e = 0; e < E_; ++e) gate[n*E_ + e] = ex[e] * inv;
        }
    }
}

// ---------------- GEMM1: global_load_lds DMA pipeline (T3/T4) ---------------
// grid 384 = 8 xcd * (8 b * 6 nt), 512 thr, all blocks resident (2/CU).
// 8 rounds of 64k. Per round: wave issues 8 async f32-row DMAs into
// fs[2][64][64] (no VGPR dst -> MLP limited by vmcnt, not registers);
// counted s_waitcnt vmcnt(8) keeps next round's 8 in flight across barriers.
// Convert phase: conflict-free ds_read -> bf16 bf[64][64] swizzled + f32
// stats. MFMA: full 256er (wave=32er), af-ring from L2-hot w1k. Epilogue
// gate*(acc - mean*cs1) + K-ext.
__global__ __launch_bounds__(512, 4) void gemm1_kernel(
        const float* __restrict__ x, const unsigned short* __restrict__ w1k,
        const float* __restrict__ gate, const float* __restrict__ cs1,
        unsigned short* __restrict__ hg) {
    __shared__ __align__(16) float fs[2][64][64];          // 32768 B (DMA dest, linear)
    __shared__ __align__(16) unsigned short bf[64][64];    // 8192 B, XOR-swizzled rows
    __shared__ float red1[8][64], red2[8][64];             // 4096 B
    __shared__ float meanS[64], sdS[64];

    const int bid = blockIdx.x;
    const int xcd = bid & 7;
    const int idx = bid >> 3;            // 0..47
    const int b   = (xcd << 3) + idx / 6;
    const int n0  = (idx % 6) * 64;

    const int tid  = threadIdx.x;
    const int lane = tid & 63;
    const int wave = tid >> 6;          // 0..7
    const int l15  = lane & 15;
    const int kgrp = lane >> 4;         // 0..3

    // DMA role: wave w stages k-rows w*8..w*8+7 of each round; lane supplies
    // the per-lane global address (column n0+lane, clamped).
    const int gn  = n0 + lane;
    const int gnc = (gn < N_) ? gn : (N_ - 1);
    const float* xb = x + (size_t)b*L_*N_ + gnc;

#define DMA(rd_) {                                                              \
    const int kb = (rd_)*64 + wave*8;                                           \
    _Pragma("unroll")                                                           \
    for (int i_ = 0; i_ < 8; ++i_)                                              \
        GLD4(xb + (size_t)(kb + i_)*N_, &fs[(rd_) & 1][wave*8 + i_][0]); }

    // Convert role: wave w reads k-slice w*8..+8, lane = n. Conflict-free
    // row reads; one u16x8 swizzled write per thread.
#define CONV(rd_) {                                                             \
    const int cur = (rd_) & 1;                                                  \
    float vv[8];                                                                \
    _Pragma("unroll")                                                           \
    for (int i_ = 0; i_ < 8; ++i_) vv[i_] = fs[cur][wave*8 + i_][lane];         \
    u16x8 pk;                                                                   \
    _Pragma("unroll")                                                           \
    for (int i_ = 0; i_ < 8; ++i_) {                                            \
        s1 += vv[i_]; s2 = fmaf(vv[i_], vv[i_], s2); pk[i_] = f2bf(vv[i_]); }   \
    *(u16x8*)((char*)&bf[lane][0] + ((wave*16) ^ ((lane & 7) << 4))) = pk; }

    float s1 = 0.f, s2 = 0.f;
    f32x4 acc[2][4];
    #pragma unroll
    for (int i = 0; i < 2; ++i)
        #pragma unroll
        for (int j = 0; j < 4; ++j) acc[i][j] = (f32x4){0.f,0.f,0.f,0.f};

    // MFMA roles: wave owns er rows wave*32..+32 x 64 n
    const unsigned short* apA = w1k + (size_t)(wave*32 + l15)*L_;
    const unsigned short* apB = w1k + (size_t)(wave*32 + 16 + l15)*L_;
    const int rsw = (l15 & 7) << 4;

    // prologue: 2 rounds of DMA in flight; convert round 0
    DMA(0); DMA(1);
    asm volatile("s_waitcnt vmcnt(8)" ::: "memory");   // round 0 landed
    __syncthreads();
    CONV(0);
    __syncthreads();

    bf16x8 af[4][2];
#define LDA(s_, kk_) { af[s_][0] = *(const bf16x8*)&apA[(kk_)*32 + kgrp*8];      \
                       af[s_][1] = *(const bf16x8*)&apB[(kk_)*32 + kgrp*8]; }
    LDA(0, 0); LDA(1, 1);

    #pragma unroll
    for (int rd = 0; rd < 8; ++rd) {
        // MFMA on round rd (2 kk of K=32 from bf)
        #pragma unroll
        for (int ks = 0; ks < 2; ++ks) {
            const int kk = rd*2 + ks;
            if (kk + 2 < 16) LDA((kk + 2) & 3, kk + 2);
            const int cbyte = ks*64 + kgrp*16;
            bf16x8 bfr[4];
            #pragma unroll
            for (int fn = 0; fn < 4; ++fn)
                bfr[fn] = *(const bf16x8*)((const char*)&bf[fn*16 + l15][0] + (cbyte ^ rsw));
            #pragma unroll
            for (int fn = 0; fn < 4; ++fn) {
                acc[0][fn] = __builtin_amdgcn_mfma_f32_16x16x32_bf16(af[kk & 3][0], bfr[fn], acc[0][fn], 0, 0, 0);
                acc[1][fn] = __builtin_amdgcn_mfma_f32_16x16x32_bf16(af[kk & 3][1], bfr[fn], acc[1][fn], 0, 0, 0);
            }
        }
        if (rd < 7) {
            if (rd + 2 < 8) {
                DMA(rd + 2);   // into fs[rd&1] (round rd's f32 already converted)
                asm volatile("s_waitcnt vmcnt(8)" ::: "memory");  // rd+1 landed
            } else {
                asm volatile("s_waitcnt vmcnt(0)" ::: "memory");  // last round
            }
            __syncthreads();   // all waves: DMA(rd+1) visible, MFMA(rd) done
            CONV(rd + 1);      // overwrite bf for next round
            __syncthreads();
        }
    }
#undef LDA
#undef DMA
#undef CONV

    // ---- stats reduce (f32-exact; accumulated during convert) ----
    red1[wave][lane] = s1;
    red2[wave][lane] = s2;
    __syncthreads();
    if (tid < 64) {
        float a = 0.f, qq = 0.f;
        #pragma unroll
        for (int kk = 0; kk < 8; ++kk) { a += red1[kk][tid]; qq += red2[kk][tid]; }
        float mean = a * (1.f/L_);
        float var = (qq - (float)L_*mean*mean) * (1.f/(L_-1));
        var = fmaxf(var, 0.f);
        meanS[tid] = mean;
        sdS[tid]   = sqrtf(var) + 1e-6f;
    }
    __syncthreads();

    // ---- epilogue: hg[b][n0+nl][er] = gate*(acc - mean*cs1), + K-ext ----
    unsigned short* hgb = hg + ((size_t)b * HGROWS + n0) * KB2;
    #pragma unroll
    for (int fm = 0; fm < 2; ++fm) {
        int er0 = wave*32 + fm*16 + kgrp*4;
        int e = er0 >> 5;
        f32x4 c4 = *(const f32x4*)&cs1[er0];
        #pragma unroll
        for (int fn = 0; fn < 4; ++fn) {
            int nl = fn*16 + l15;
            int gnn = n0 + nl; if (gnn > N_-1) gnn = N_-1;
            float g = gate[gnn*E_ + e];
            float m = meanS[nl];
            u16x4 pk;
            #pragma unroll
            for (int j = 0; j < 4; ++j)
                pk[j] = f2bf(g * (acc[fm][fn][j] - m * c4[j]));
            *(u16x4*)&hgb[(size_t)nl*KB2 + er0] = pk;
        }
    }
    {   // K-extension cols 256..287: 64 rows x 8 segs (512 threads)
        int nl = tid >> 3, seg = tid & 7;
        int gnn = n0 + nl; if (gnn > N_-1) gnn = N_-1;
        float sd = sdS[nl], m = meanS[nl];
        u16x4 pk;
        #pragma unroll
        for (int jj = 0; jj < 4; ++jj) {
            int k = seg*4 + jj;
            float vv = (k < E_) ? gate[gnn*E_ + k] * sd : ((k == E_) ? m : 0.f);
            pk[jj] = f2bf(vv);
        }
        *(u16x4*)&hgb[(size_t)nl*KB2 + ER_ + seg*4] = pk;
    }
}

// ---------------- GEMM2: out = w2x . hg^T, one LDS stage + barrier ----------
// grid 2304 = 8 xcd * (8 b * (6 pt * 6 nt)); BM=128 p, BN=64 n, K=288.
#define HGS 296   // u16 LDS stride (148 dw -> 2-way aliasing, free)
__global__ __launch_bounds__(512, 6) void gemm2_kernel(
        const unsigned short* __restrict__ hg, const unsigned short* __restrict__ w2x,
        float* __restrict__ out) {
    __shared__ __align__(16) char smem[64 * HGS * 2];      // 37888 B
    unsigned short* hgL = (unsigned short*)smem;           // [64][296]
    const int bid = blockIdx.x;
    const int xcd = bid & 7;
    const int idx = bid >> 3;            // 0..287
    const int b   = (xcd << 3) + idx / 36;
    const int rem = idx % 36;
    const int p0  = (rem / 6) * 128;
    const int n0  = (rem % 6) * 64;

    const int tid  = threadIdx.x;
    const int lane = tid & 63;
    const int wave = tid >> 6;
    const int l15  = lane & 15;
    const int kgrp = lane >> 4;

    // stage hg tile [64][288] -> LDS (16B chunks, 36 per row)
    const unsigned short* hgb = hg + ((size_t)b * HGROWS + n0) * KB2;
    #pragma unroll
    for (int it = 0; it < 5; ++it) {
        int c = tid + it*512;
        if (c < 64*36) {
            int row = c / 36, col = c % 36;
            *(u16x8*)&hgL[(size_t)row*HGS + col*8] =
                *(const u16x8*)&hgb[(size_t)row*KB2 + col*8];
        }
    }
    __syncthreads();

    // K-loop: wave owns 16 p-rows; A-frags from L2-hot w2x, B-frags from LDS
    int prow = p0 + wave*16 + l15; if (prow > P_-1) prow = P_-1;
    const unsigned short* ap = w2x + (size_t)prow*KB2;
    f32x4 o[4];
    #pragma unroll
    for (int j = 0; j < 4; ++j) o[j] = (f32x4){0.f,0.f,0.f,0.f};
    #pragma unroll
    for (int ks = 0; ks < 9; ++ks) {
        bf16x8 afr = *(const bf16x8*)&ap[ks*32 + kgrp*8];
        #pragma unroll
        for (int fn = 0; fn < 4; ++fn) {
            bf16x8 bfr = *(const bf16x8*)&hgL[(size_t)(fn*16 + l15)*HGS + ks*32 + kgrp*8];
            o[fn] = __builtin_amdgcn_mfma_f32_16x16x32_bf16(afr, bfr, o[fn], 0, 0, 0);
        }
    }
    __syncthreads();   // all waves done reading hgL; patch may overwrite

    // patch-transpose: D rows p_loc = kgrp*4+j, cols n_loc = fn*16+l15
    float* patch = (float*)smem + wave * 1088;   // [16][68] f32 = 4352 B
    #pragma unroll
    for (int fn = 0; fn < 4; ++fn)
        #pragma unroll
        for (int j = 0; j < 4; ++j)
            patch[(kgrp*4 + j)*68 + fn*16 + l15] = o[fn][j];
    const int pw0 = p0 + wave*16;
    #pragma unroll
    for (int pass = 0; pass < 4; ++pass) {
        int ploc = pass*4 + kgrp;
        f32x4 v = *(const f32x4*)&patch[ploc*68 + l15*4];
        int p = pw0 + ploc;
        int n = n0 + l15*4;
        if (p < P_) {
            float* orow = out + ((size_t)b*P_ + p)*N_;
            if (n + 3 < N_) {
                *(f32x4*)&orow[n] = v;
            } else {
                #pragma unroll
                for (int j = 0; j < 4; ++j)
                    if (n + j < N_) orow[n + j] = v[j];
            }
        }
    }
}

extern "C" void kernel_launch(void* const* d_in, const int* in_sizes, int n_in,
                              void* d_out, int out_size, void* d_ws, size_t ws_size,
                              hipStream_t stream) {
    const float* x     = (const float*)d_in[0];
    const float* ident = (const float*)d_in[1];
    const float* rw1   = (const float*)d_in[2];
    const float* rb1   = (const float*)d_in[3];
    const float* rw2   = (const float*)d_in[4];
    const float* rb2   = (const float*)d_in[5];
    const float* w1    = (const float*)d_in[6];
    const float* w2    = (const float*)d_in[7];
    const float* bias  = (const float*)d_in[8];
    float* out = (float*)d_out;
    float* ws  = (float*)d_ws;

    float* gate = ws + OFF_GATE;
    float* cs1  = ws + OFF_CS1;
    unsigned short* w1k = (unsigned short*)(ws + OFF_W1K);
    unsigned short* w2x = (unsigned short*)(ws + OFF_W2X);
    unsigned short* hg  = (unsigned short*)(ws + OFF_HG);

    prep_kernel<<<856 + N_, 512, 0, stream>>>(w1, w2, bias, ident, rw1, rb1,
                                              rw2, rb2, w1k, w2x, cs1, gate);
    gemm1_kernel<<<dim3(384), 512, 0, stream>>>(x, w1k, gate, cs1, hg);
    gemm2_kernel<<<dim3(2304), 512, 0, stream>>>(hg, w2x, out);
}

// Round 23
// 61.740 us; speedup vs baseline: 1.0910x; 1.0422x over previous
//
#include <hip/hip_runtime.h>
#include <math.h>

#define B_ 64
#define L_ 512
#define N_ 321
#define P_ 720
#define E_ 8
#define R_ 32
#define CID_ 32
#define H_ 64
#define ER_ 256
#define KB2 288      // ER_ + 8 bias-rank + 1 mean + 23 zero-pad
#define HGROWS 384   // 6 n-tiles x 64 (rows >= N_ hold dup/junk, never used)

typedef __attribute__((ext_vector_type(8))) short bf16x8;
typedef __attribute__((ext_vector_type(4))) float f32x4;
typedef __attribute__((ext_vector_type(8))) unsigned short u16x8;
typedef __attribute__((ext_vector_type(4))) unsigned short u16x4;

// workspace layout (float offsets)
#define OFF_GATE 0                        // 2568
#define OFF_CS1  2568                     // 256
#define OFF_W1K  2824                     // bf16 256*512 = 65536 f
#define OFF_W2X  68360                    // bf16 720*288 = 103680 f
#define OFF_HG   172040                   // bf16 64*384*288 = 3538944 f
// total ~14.8 MB

__device__ __forceinline__ unsigned short f2bf(float f) {
    unsigned u = __float_as_uint(f);
    u += 0x7fffu + ((u >> 16) & 1u);
    return (unsigned short)(u >> 16);
}
__device__ __forceinline__ float bf2f(unsigned short h) {
    return __uint_as_float(((unsigned)h) << 16);
}

// async global->LDS DMA: per-lane global src, wave-uniform LDS base + lane*4
#define GLD4(gsrc, ldst)                                                        \
    __builtin_amdgcn_global_load_lds(                                           \
        (const __attribute__((address_space(1))) unsigned*)(gsrc),              \
        (__attribute__((address_space(3))) unsigned*)(ldst), 4, 0, 0)

// ---------------- prep: w1k, w2x, cs1, router (merged) ----------------------
__global__ void prep_kernel(const float* __restrict__ w1, const float* __restrict__ w2,
                            const float* __restrict__ bias,
                            const float* __restrict__ ident,
                            const float* __restrict__ rw1, const float* __restrict__ rb1,
                            const float* __restrict__ rw2, const float* __restrict__ rb2,
                            unsigned short* __restrict__ w1k, unsigned short* __restrict__ w2x,
                            float* __restrict__ cs1, float* __restrict__ gate) {
    __shared__ float red[16][32];
    __shared__ float hid[H_];
    __shared__ float lg[E_];
    int bid = blockIdx.x, t = threadIdx.x;
    if (bid < 128) {                  // w1k [er][l]: 256*512 elems, 512 thr x 2
        #pragma unroll
        for (int r = 0; r < 2; ++r) {
            int g = bid*1024 + r*512 + t;
            int er = g >> 9, l = g & 511;
            w1k[g] = f2bf(w1[(size_t)(er >> 5)*(L_*R_) + (size_t)l*R_ + (er & 31)]);
        }
    } else if (bid < 848) {           // w2x row p: K-extended
        int p = bid - 128;
        if (t < KB2) {
            unsigned short v;
            if (t < ER_)            v = f2bf(w2[(size_t)t*P_ + p]);
            else if (t < ER_ + E_)  v = f2bf(bias[(size_t)(t - ER_)*P_ + p]);
            else if (t == ER_ + E_) v = 0x3f80;  // bf16(1.0) for the mean lane
            else                    v = 0;
            w2x[(size_t)p*KB2 + t] = v;
        }
    } else if (bid < 856) {           // cs1: 8 blocks, one expert each (512 thr)
        int e = bid - 848;
        int q = t >> 5, r = t & 31;
        float s = 0.f;
        for (int l = q; l < L_; l += 16)
            s += bf2f(f2bf(w1[(size_t)e*(L_*R_) + (size_t)l*R_ + r]));
        red[q][r] = s;
        __syncthreads();
        if (q == 0) {
            #pragma unroll
            for (int qq = 1; qq < 16; ++qq) s += red[qq][r];
            cs1[e*32 + r] = s;
        }
    } else {                          // router: one n per block (t<64 active)
        int n = bid - 856;
        if (t < H_) {
            float acc = rb1[t];
            #pragma unroll
            for (int c = 0; c < CID_; ++c)
                acc = fmaf(ident[n*CID_ + c], rw1[c*H_ + t], acc);
            hid[t] = fmaxf(acc, 0.f);
        }
        __syncthreads();
        if (t < E_) {
            float a = rb2[t];
            #pragma unroll
            for (int h = 0; h < H_; ++h) a = fmaf(hid[h], rw2[h*E_ + t], a);
            lg[t] = a;
        }
        __syncthreads();
        if (t == 0) {
            float m = lg[0];
            #pragma unroll
            for (int e = 1; e < E_; ++e) m = fmaxf(m, lg[e]);
            float s = 0.f, ex[E_];
            #pragma unroll
            for (int e = 0; e < E_; ++e) { ex[e] = expf(lg[e] - m); s += ex[e]; }
            float inv = 1.f / s;
            #pragma unroll
            for (int e = 0; e < E_; ++e) gate[n*E_ + e] = ex[e] * inv;
        }
    }
}

// ---------------- GEMM1: DMA pipeline, fs ring-3 + bf dbuf ------------------
// grid 384 = 8 xcd * (8 b * 6 nt), 512 thr, ~70KB LDS -> 2 blocks/CU.
// 8 rounds of 64k. Steady state per round rd:
//   DMA(rd+2) -> fs[(rd+2)%3]  (async, no VGPR dst)
//   vmcnt(8): round rd+1's 8 DMAs landed (rd+2's stay in flight)
//   CONV(rd+1): fs[(rd+1)%3] -> bf[(rd+1)&1] bf16 swizzled + f32 stats
//   MFMA(rd) on bf[rd&1]   (disjoint from CONV's buffer -> cross-wave overlap)
//   one barrier.
__global__ __launch_bounds__(512, 4) void gemm1_kernel(
        const float* __restrict__ x, const unsigned short* __restrict__ w1k,
        const float* __restrict__ gate, const float* __restrict__ cs1,
        unsigned short* __restrict__ hg) {
    __shared__ __align__(16) float fs[3][64][64];          // 49152 B (DMA dest, linear)
    __shared__ __align__(16) unsigned short bf[2][64][64]; // 16384 B, XOR-swizzled rows
    __shared__ float red1[8][64], red2[8][64];             // 4096 B
    __shared__ float meanS[64], sdS[64];

    const int bid = blockIdx.x;
    const int xcd = bid & 7;
    const int idx = bid >> 3;            // 0..47
    const int b   = (xcd << 3) + idx / 6;
    const int n0  = (idx % 6) * 64;

    const int tid  = threadIdx.x;
    const int lane = tid & 63;
    const int wave = tid >> 6;          // 0..7
    const int l15  = lane & 15;
    const int kgrp = lane >> 4;         // 0..3

    // DMA role: wave w stages k-rows w*8..w*8+7 of each round; lane supplies
    // the per-lane global address (column n0+lane, clamped).
    const int gn  = n0 + lane;
    const int gnc = (gn < N_) ? gn : (N_ - 1);
    const float* xb = x + (size_t)b*L_*N_ + gnc;

#define DMA(rd_) {                                                              \
    const int kb = (rd_)*64 + wave*8;                                           \
    _Pragma("unroll")                                                           \
    for (int i_ = 0; i_ < 8; ++i_)                                              \
        GLD4(xb + (size_t)(kb + i_)*N_, &fs[(rd_) % 3][wave*8 + i_][0]); }

#define CONV(rd_) {                                                             \
    const int cur = (rd_) % 3;                                                  \
    float vv[8];                                                                \
    _Pragma("unroll")                                                           \
    for (int i_ = 0; i_ < 8; ++i_) vv[i_] = fs[cur][wave*8 + i_][lane];         \
    u16x8 pk;                                                                   \
    _Pragma("unroll")                                                           \
    for (int i_ = 0; i_ < 8; ++i_) {                                            \
        s1 += vv[i_]; s2 = fmaf(vv[i_], vv[i_], s2); pk[i_] = f2bf(vv[i_]); }   \
    *(u16x8*)((char*)&bf[(rd_) & 1][lane][0] + ((wave*16) ^ ((lane & 7) << 4))) = pk; }

    float s1 = 0.f, s2 = 0.f;
    f32x4 acc[2][4];
    #pragma unroll
    for (int i = 0; i < 2; ++i)
        #pragma unroll
        for (int j = 0; j < 4; ++j) acc[i][j] = (f32x4){0.f,0.f,0.f,0.f};

    // MFMA roles: wave owns er rows wave*32..+32 x 64 n
    const unsigned short* apA = w1k + (size_t)(wave*32 + l15)*L_;
    const unsigned short* apB = w1k + (size_t)(wave*32 + 16 + l15)*L_;
    const int rsw = (l15 & 7) << 4;

    // prologue: rounds 0,1 DMA'd; convert round 0
    DMA(0); DMA(1);
    asm volatile("s_waitcnt vmcnt(8)" ::: "memory");   // round 0 landed
    __builtin_amdgcn_sched_barrier(0);
    CONV(0);
    __syncthreads();

    bf16x8 af[4][2];
#define LDA(s_, kk_) { af[s_][0] = *(const bf16x8*)&apA[(kk_)*32 + kgrp*8];      \
                       af[s_][1] = *(const bf16x8*)&apB[(kk_)*32 + kgrp*8]; }
    LDA(0, 0); LDA(1, 1);

    #pragma unroll
    for (int rd = 0; rd < 8; ++rd) {
        if (rd + 2 < 8) DMA(rd + 2);        // async into fs[(rd+2)%3]
        if (rd < 7) {
            if (rd + 2 < 8) {
                asm volatile("s_waitcnt vmcnt(8)" ::: "memory");  // rd+1 landed
            } else {
                asm volatile("s_waitcnt vmcnt(0)" ::: "memory");  // last round
            }
            __builtin_amdgcn_sched_barrier(0);
            CONV(rd + 1);                   // writes bf[(rd+1)&1]
        }
        // MFMA on round rd (2 kk of K=32 from bf[rd&1])
        #pragma unroll
        for (int ks = 0; ks < 2; ++ks) {
            const int kk = rd*2 + ks;
            if (kk + 2 < 16) LDA((kk + 2) & 3, kk + 2);
            const int cbyte = ks*64 + kgrp*16;
            bf16x8 bfr[4];
            #pragma unroll
            for (int fn = 0; fn < 4; ++fn)
                bfr[fn] = *(const bf16x8*)((const char*)&bf[rd & 1][fn*16 + l15][0] + (cbyte ^ rsw));
            #pragma unroll
            for (int fn = 0; fn < 4; ++fn) {
                acc[0][fn] = __builtin_amdgcn_mfma_f32_16x16x32_bf16(af[kk & 3][0], bfr[fn], acc[0][fn], 0, 0, 0);
                acc[1][fn] = __builtin_amdgcn_mfma_f32_16x16x32_bf16(af[kk & 3][1], bfr[fn], acc[1][fn], 0, 0, 0);
            }
        }
        __syncthreads();   // CONV(rd+1) visible to all; bf[rd&1] free for CONV(rd+2)
    }
#undef LDA
#undef DMA
#undef CONV

    // ---- stats reduce (f32-exact; accumulated during convert) ----
    red1[wave][lane] = s1;
    red2[wave][lane] = s2;
    __syncthreads();
    if (tid < 64) {
        float a = 0.f, qq = 0.f;
        #pragma unroll
        for (int kk = 0; kk < 8; ++kk) { a += red1[kk][tid]; qq += red2[kk][tid]; }
        float mean = a * (1.f/L_);
        float var = (qq - (float)L_*mean*mean) * (1.f/(L_-1));
        var = fmaxf(var, 0.f);
        meanS[tid] = mean;
        sdS[tid]   = sqrtf(var) + 1e-6f;
    }
    __syncthreads();

    // ---- epilogue: hg[b][n0+nl][er] = gate*(acc - mean*cs1), + K-ext ----
    unsigned short* hgb = hg + ((size_t)b * HGROWS + n0) * KB2;
    #pragma unroll
    for (int fm = 0; fm < 2; ++fm) {
        int er0 = wave*32 + fm*16 + kgrp*4;
        int e = er0 >> 5;
        f32x4 c4 = *(const f32x4*)&cs1[er0];
        #pragma unroll
        for (int fn = 0; fn < 4; ++fn) {
            int nl = fn*16 + l15;
            int gnn = n0 + nl; if (gnn > N_-1) gnn = N_-1;
            float g = gate[gnn*E_ + e];
            float m = meanS[nl];
            u16x4 pk;
            #pragma unroll
            for (int j = 0; j < 4; ++j)
                pk[j] = f2bf(g * (acc[fm][fn][j] - m * c4[j]));
            *(u16x4*)&hgb[(size_t)nl*KB2 + er0] = pk;
        }
    }
    {   // K-extension cols 256..287: 64 rows x 8 segs (512 threads)
        int nl = tid >> 3, seg = tid & 7;
        int gnn = n0 + nl; if (gnn > N_-1) gnn = N_-1;
        float sd = sdS[nl], m = meanS[nl];
        u16x4 pk;
        #pragma unroll
        for (int jj = 0; jj < 4; ++jj) {
            int k = seg*4 + jj;
            float vv = (k < E_) ? gate[gnn*E_ + k] * sd : ((k == E_) ? m : 0.f);
            pk[jj] = f2bf(vv);
        }
        *(u16x4*)&hgb[(size_t)nl*KB2 + ER_ + seg*4] = pk;
    }
}

// ---------------- GEMM2: out = w2x . hg^T, one LDS stage + barrier ----------
// grid 2304 = 8 xcd * (8 b * (6 pt * 6 nt)); BM=128 p, BN=64 n, K=288.
#define HGS 296   // u16 LDS stride (148 dw -> 2-way aliasing, free)
__global__ __launch_bounds__(512, 6) void gemm2_kernel(
        const unsigned short* __restrict__ hg, const unsigned short* __restrict__ w2x,
        float* __restrict__ out) {
    __shared__ __align__(16) char smem[64 * HGS * 2];      // 37888 B
    unsigned short* hgL = (unsigned short*)smem;           // [64][296]
    const int bid = blockIdx.x;
    const int xcd = bid & 7;
    const int idx = bid >> 3;            // 0..287
    const int b   = (xcd << 3) + idx / 36;
    const int rem = idx % 36;
    const int p0  = (rem / 6) * 128;
    const int n0  = (rem % 6) * 64;

    const int tid  = threadIdx.x;
    const int lane = tid & 63;
    const int wave = tid >> 6;
    const int l15  = lane & 15;
    const int kgrp = lane >> 4;

    // stage hg tile [64][288] -> LDS (16B chunks, 36 per row)
    const unsigned short* hgb = hg + ((size_t)b * HGROWS + n0) * KB2;
    #pragma unroll
    for (int it = 0; it < 5; ++it) {
        int c = tid + it*512;
        if (c < 64*36) {
            int row = c / 36, col = c % 36;
            *(u16x8*)&hgL[(size_t)row*HGS + col*8] =
                *(const u16x8*)&hgb[(size_t)row*KB2 + col*8];
        }
    }
    __syncthreads();

    // K-loop: wave owns 16 p-rows; A-frags from L2-hot w2x, B-frags from LDS
    int prow = p0 + wave*16 + l15; if (prow > P_-1) prow = P_-1;
    const unsigned short* ap = w2x + (size_t)prow*KB2;
    f32x4 o[4];
    #pragma unroll
    for (int j = 0; j < 4; ++j) o[j] = (f32x4){0.f,0.f,0.f,0.f};
    #pragma unroll
    for (int ks = 0; ks < 9; ++ks) {
        bf16x8 afr = *(const bf16x8*)&ap[ks*32 + kgrp*8];
        #pragma unroll
        for (int fn = 0; fn < 4; ++fn) {
            bf16x8 bfr = *(const bf16x8*)&hgL[(size_t)(fn*16 + l15)*HGS + ks*32 + kgrp*8];
            o[fn] = __builtin_amdgcn_mfma_f32_16x16x32_bf16(afr, bfr, o[fn], 0, 0, 0);
        }
    }
    __syncthreads();   // all waves done reading hgL; patch may overwrite

    // patch-transpose: D rows p_loc = kgrp*4+j, cols n_loc = fn*16+l15
    float* patch = (float*)smem + wave * 1088;   // [16][68] f32 = 4352 B
    #pragma unroll
    for (int fn = 0; fn < 4; ++fn)
        #pragma unroll
        for (int j = 0; j < 4; ++j)
            patch[(kgrp*4 + j)*68 + fn*16 + l15] = o[fn][j];
    const int pw0 = p0 + wave*16;
    #pragma unroll
    for (int pass = 0; pass < 4; ++pass) {
        int ploc = pass*4 + kgrp;
        f32x4 v = *(const f32x4*)&patch[ploc*68 + l15*4];
        int p = pw0 + ploc;
        int n = n0 + l15*4;
        if (p < P_) {
            float* orow = out + ((size_t)b*P_ + p)*N_;
            if (n + 3 < N_) {
                *(f32x4*)&orow[n] = v;
            } else {
                #pragma unroll
                for (int j = 0; j < 4; ++j)
                    if (n + j < N_) orow[n + j] = v[j];
            }
        }
    }
}

extern "C" void kernel_launch(void* const* d_in, const int* in_sizes, int n_in,
                              void* d_out, int out_size, void* d_ws, size_t ws_size,
                              hipStream_t stream) {
    const float* x     = (const float*)d_in[0];
    const float* ident = (const float*)d_in[1];
    const float* rw1   = (const float*)d_in[2];
    const float* rb1   = (const float*)d_in[3];
    const float* rw2   = (const float*)d_in[4];
    const float* rb2   = (const float*)d_in[5];
    const float* w1    = (const float*)d_in[6];
    const float* w2    = (const float*)d_in[7];
    const float* bias  = (const float*)d_in[8];
    float* out = (float*)d_out;
    float* ws  = (float*)d_ws;

    float* gate = ws + OFF_GATE;
    float* cs1  = ws + OFF_CS1;
    unsigned short* w1k = (unsigned short*)(ws + OFF_W1K);
    unsigned short* w2x = (unsigned short*)(ws + OFF_W2X);
    unsigned short* hg  = (unsigned short*)(ws + OFF_HG);

    prep_kernel<<<856 + N_, 512, 0, stream>>>(w1, w2, bias, ident, rw1, rb1,
                                              rw2, rb2, w1k, w2x, cs1, gate);
    gemm1_kernel<<<dim3(384), 512, 0, stream>>>(x, w1k, gate, cs1, hg);
    gemm2_kernel<<<dim3(2304), 512, 0, stream>>>(hg, w2x, out);
}